// Round 16
// baseline (174.810 us; speedup 1.0000x reference)
//
#include <hip/hip_runtime.h>

#define EPSV 1e-5f

typedef __attribute__((ext_vector_type(8))) short short8;
typedef __attribute__((ext_vector_type(4))) short s16x4;
typedef __attribute__((ext_vector_type(4))) float f32x4;
typedef unsigned short ushort_t;

__device__ inline ushort_t f2bf(float f) {
    unsigned int x = __builtin_bit_cast(unsigned int, f);
    unsigned int r = (x + 0x7fffu + ((x >> 16) & 1u)) >> 16;
    return (ushort_t)r;
}
__device__ inline float bf2f(ushort_t u) {
    return __builtin_bit_cast(float, (unsigned int)u << 16);
}

// ---- weight prep (col-interleaved layouts) + time embedding (block 720) ----
__global__ __launch_bounds__(256) void k_prep(
    const float* __restrict__ w_fuse, const float* __restrict__ w3,
    const float* __restrict__ wup,
    const float* __restrict__ tin, const float* __restrict__ w_temb,
    const float* __restrict__ b_temb, float* __restrict__ emb,
    ushort_t* __restrict__ wfuset2, ushort_t* __restrict__ w3t2,
    ushort_t* __restrict__ wupt, ushort_t* __restrict__ wupt2) {
    if (blockIdx.x == 720) {
        __shared__ float st[8 * 256];
        int t = threadIdx.x;
        for (int i = t; i < 2048; i += 256) { float v = tin[i]; st[i] = v / (1.f + __expf(-v)); }
        __syncthreads();
        for (int p = t; p < 512; p += 256) {
            int bb = p >> 6, c = p & 63;
            float acc = b_temb[c];
            for (int e = 0; e < 256; e++) acc += st[bb * 256 + e] * w_temb[e * 64 + c];
            emb[bb * 64 + c] = acc;
        }
        return;
    }
    int i = blockIdx.x * 256 + threadIdx.x;
    if (i < 8192) {
        int kk = i & 127, ln = (i >> 7) & 15, j = i >> 11;
        wfuset2[i] = f2bf(w_fuse[kk * 64 + 4 * ln + j]);
    } else if (i < 118784) {
        int p = i - 8192;
        int kk = p & 63, ln = (p >> 6) & 15, j = (p >> 10) & 3, k = p >> 12;
        w3t2[p] = f2bf(w3[k * 4096 + kk * 64 + 4 * ln + j]);
    } else if (i < 151552) {
        int p = i - 118784;
        int uk = p >> 12, r = p & 4095, f = r >> 6, c = r & 63;
        wupt[p] = f2bf(wup[uk * 4096 + c * 64 + f]);
    } else if (i < 184320) {
        int p = i - 151552;
        int kk = p & 63, ln = (p >> 6) & 15, j = (p >> 10) & 3, uk = p >> 12;
        wupt2[p] = f2bf(wup[uk * 4096 + kk * 64 + 4 * ln + j]);
    }
}

// ---- K1: T(bf16) = feats @ w_fuse. Row-owning waves, direct loads. ----
__global__ __launch_bounds__(256) void k_gemm_fuse(
    const float* __restrict__ feats, const ushort_t* __restrict__ wfuset2,
    ushort_t* __restrict__ T, float* __restrict__ partialT, int npts) {
    __shared__ float sm[4][128];
    int t = threadIdx.x, bid = blockIdx.x;
    int lane = t & 63, w = t >> 6, q = lane >> 4, ln = lane & 15;
    int rbase = bid * 64 + w * 16;
    int row = rbase + ln;
    bool rv = row < npts;
    short8 afr[4];
#pragma unroll
    for (int s = 0; s < 4; s++) {
        short8 v = (short8)0;
        if (rv) {
            const float* src = feats + (size_t)row * 128 + s * 32 + q * 8;
            float4 a = *(const float4*)src;
            float4 b = *(const float4*)(src + 4);
            ushort_t u[8] = {f2bf(a.x), f2bf(a.y), f2bf(a.z), f2bf(a.w),
                             f2bf(b.x), f2bf(b.y), f2bf(b.z), f2bf(b.w)};
            v = *(short8*)u;
        }
        afr[s] = v;
    }
    f32x4 acc[4];
#pragma unroll
    for (int j = 0; j < 4; j++) acc[j] = (f32x4)0.f;
#pragma unroll
    for (int s = 0; s < 4; s++)
#pragma unroll
        for (int j = 0; j < 4; j++) {
            short8 bfr = *(const short8*)&wfuset2[j * 2048 + ln * 128 + s * 32 + q * 8];
            acc[j] = __builtin_amdgcn_mfma_f32_16x16x32_bf16(afr[s], bfr, acc[j], 0, 0, 0);
        }
    float ps[4] = {0, 0, 0, 0}, pq[4] = {0, 0, 0, 0};
#pragma unroll
    for (int r = 0; r < 4; r++) {
        int rr = rbase + q * 4 + r;
        ushort_t o[4];
#pragma unroll
        for (int j = 0; j < 4; j++) {
            float v = acc[j][r];
            ps[j] += v; pq[j] += v * v;
            o[j] = f2bf(v);
        }
        if (rr < npts) *(s16x4*)&T[(size_t)rr * 64 + 4 * ln] = *(s16x4*)o;
    }
#pragma unroll
    for (int j = 0; j < 4; j++) {
        ps[j] += __shfl_xor(ps[j], 16); ps[j] += __shfl_xor(ps[j], 32);
        pq[j] += __shfl_xor(pq[j], 16); pq[j] += __shfl_xor(pq[j], 32);
    }
    if (lane < 16) {
#pragma unroll
        for (int j = 0; j < 4; j++) {
            sm[w][ln * 4 + j] = ps[j];
            sm[w][64 + ln * 4 + j] = pq[j];
        }
    }
    __syncthreads();
    if (t < 128)
        partialT[(size_t)t * 2048 + bid] = sm[0][t] + sm[1][t] + sm[2][t] + sm[3][t];
}

// ---- finalize BN: 64 blocks, one channel each; coalesced reads of partialT ----
__global__ __launch_bounds__(256) void k_finalize(
    const float* __restrict__ partialT, int nrows, float inv_count,
    const float* __restrict__ g, const float* __restrict__ b, float* __restrict__ prm) {
    int c = blockIdx.x;
    int t = threadIdx.x;
    float S = 0.f, Q = 0.f;
    for (int r = t; r < nrows; r += 256) {
        S += partialT[(size_t)c * 2048 + r];
        Q += partialT[(size_t)(64 + c) * 2048 + r];
    }
#pragma unroll
    for (int d = 1; d < 64; d <<= 1) { S += __shfl_xor(S, d); Q += __shfl_xor(Q, d); }
    __shared__ float sS[4], sQ[4];
    int w = t >> 6;
    if ((t & 63) == 0) { sS[w] = S; sQ[w] = Q; }
    __syncthreads();
    if (t == 0) {
        float s = sS[0] + sS[1] + sS[2] + sS[3];
        float qq = sQ[0] + sQ[1] + sQ[2] + sQ[3];
        float mean = s * inv_count;
        float var = qq * inv_count - mean * mean;
        float scale = g[c] * rsqrtf(var + EPSV);
        prm[c] = scale;
        prm[64 + c] = b[c] - mean * scale;
    }
}

// ---- apply BN1 + ReLU + emb -> h (bf16) ----
__global__ __launch_bounds__(256) void k_apply1(
    const ushort_t* __restrict__ T, const float* __restrict__ prm,
    const float* __restrict__ emb, const int* __restrict__ bidx,
    ushort_t* __restrict__ h, int npts) {
    int tid = blockIdx.x * 256 + threadIdx.x;
    if (tid >= npts * 8) return;
    int row = tid >> 3, c0 = (tid & 7) * 8;
    int bi = bidx[row];
    short8 x = *(const short8*)&T[(size_t)row * 64 + c0];
    ushort_t o[8];
#pragma unroll
    for (int j = 0; j < 8; j++) {
        int c = c0 + j;
        float v = prm[c] * bf2f((ushort_t)x[j]) + prm[64 + c];
        v = fmaxf(v, 0.f) + emb[bi * 64 + c];
        o[j] = f2bf(v);
    }
    *(short8*)&h[(size_t)row * 64 + c0] = *(short8*)o;
}

// ---- K4: 27-offset gather-GEMM. 8 waves x 16 rows = 128 rows/block (782 blocks
//      -> 16 waves/CU vs 12.2 at 256 rows), LDS-staged B (dbuf), exec-masked gathers. ----
__global__ __launch_bounds__(512, 2) void k_conv27(
    const ushort_t* __restrict__ h, const ushort_t* __restrict__ w3t2,
    const int* __restrict__ nbr,
    ushort_t* __restrict__ out2, float* __restrict__ partialT, int npts) {
    __shared__ ushort_t Bl[2][4 * 4096];   // 2 x 32 KB, fragment-major per k-tile
    __shared__ float sm[8][128];
    int nwg = gridDim.x;
    int qc = nwg >> 3, rm = nwg & 7;
    int xcd = blockIdx.x & 7, pos = blockIdx.x >> 3;
    int bid = (xcd < rm ? xcd * (qc + 1) : rm * (qc + 1) + (xcd - rm) * qc) + pos;
    int t = threadIdx.x;
    int lane = t & 63, w = t >> 6, q = lane >> 4, ln = lane & 15;
    int rbase = bid * 128 + w * 16;
    int row0 = rbase + ln;
    bool rv0 = row0 < npts;
    // fragment-major staging map (verified R6): dest byte D = t*16
    int D = t * 16;
    int blk = D >> 10, lane_d = (D >> 4) & 63;
    int srcByte = (blk >> 1) * 2048 + (lane_d & 15) * 128 + (blk & 1) * 64 + (lane_d >> 4) * 16;
    const char* wsrc = (const char*)w3t2 + srcByte;
    char* lbase0 = (char*)&Bl[0][0] + (size_t)w * 1024;  // wave-uniform; HW adds lane*16
    char* lbase1 = (char*)&Bl[1][0] + (size_t)w * 1024;
#define STAGE(kk, slot, bufp) \
    __builtin_amdgcn_global_load_lds((const unsigned int*)(wsrc + (size_t)(kk) * 8192), \
                                     (unsigned int*)((bufp) + (size_t)(slot) * 8192), 16, 0, 0)
    STAGE(0, 0, lbase0); STAGE(1, 1, lbase0); STAGE(2, 2, lbase0); STAGE(3, 3, lbase0);
    f32x4 acc[4];
#pragma unroll
    for (int j = 0; j < 4; j++) acc[j] = (f32x4)0.f;
    __syncthreads();   // staging of chunk 0 complete
#pragma unroll
    for (int c = 0; c < 7; c++) {
        const int nk = (c == 6) ? 3 : 4;
        int id0[4];
#pragma unroll
        for (int r = 0; r < 4; r++)
            if (r < nk) {
                int kk = c * 4 + r;
                id0[r] = rv0 ? nbr[(size_t)kk * npts + row0] : -1;
            }
        if (c < 6) {
            const int nkn = (c == 5) ? 3 : 4;
            char* nb = ((c + 1) & 1) ? lbase1 : lbase0;
#pragma unroll
            for (int r = 0; r < 4; r++)
                if (r < nkn) STAGE(4 * (c + 1) + r, r, nb);
        }
        const ushort_t* bl = (c & 1) ? &Bl[1][0] : &Bl[0][0];
#pragma unroll
        for (int r = 0; r < 4; r++) {
            if (r < nk) {
                if (__any(id0[r] >= 0)) {
                    // exec-masked gathers: only valid lanes fetch
                    short8 a00 = (short8)0, a01 = (short8)0;
                    if (id0[r] >= 0) {
                        const ushort_t* hp0 = h + (size_t)id0[r] * 64 + q * 8;
                        a00 = *(const short8*)hp0;
                        a01 = *(const short8*)(hp0 + 32);
                    }
                    const ushort_t* bt = bl + r * 4096;
#pragma unroll
                    for (int j = 0; j < 4; j++) {
                        short8 b0 = *(const short8*)&bt[(j * 2 + 0) * 512 + lane * 8];
                        short8 b1 = *(const short8*)&bt[(j * 2 + 1) * 512 + lane * 8];
                        acc[j] = __builtin_amdgcn_mfma_f32_16x16x32_bf16(a00, b0, acc[j], 0, 0, 0);
                        acc[j] = __builtin_amdgcn_mfma_f32_16x16x32_bf16(a01, b1, acc[j], 0, 0, 0);
                    }
                }
            }
        }
        __syncthreads();   // next buffer staged + all waves done with this one
    }
#undef STAGE
    float ps[4] = {0, 0, 0, 0}, pq[4] = {0, 0, 0, 0};
#pragma unroll
    for (int r = 0; r < 4; r++) {
        int rr = rbase + q * 4 + r;
        ushort_t o[4];
#pragma unroll
        for (int j = 0; j < 4; j++) {
            float v = acc[j][r];
            ps[j] += v; pq[j] += v * v;
            o[j] = f2bf(v);
        }
        if (rr < npts) *(s16x4*)&out2[(size_t)rr * 64 + 4 * ln] = *(s16x4*)o;
    }
#pragma unroll
    for (int j = 0; j < 4; j++) {
        ps[j] += __shfl_xor(ps[j], 16); ps[j] += __shfl_xor(ps[j], 32);
        pq[j] += __shfl_xor(pq[j], 16); pq[j] += __shfl_xor(pq[j], 32);
    }
    if (lane < 16) {
#pragma unroll
        for (int j = 0; j < 4; j++) {
            sm[w][ln * 4 + j] = ps[j];
            sm[w][64 + ln * 4 + j] = pq[j];
        }
    }
    __syncthreads();
    if (t < 128) {
        float s = 0.f;
#pragma unroll
        for (int i = 0; i < 8; i++) s += sm[i][t];
        partialT[(size_t)t * 2048 + bid] = s;
    }
}

// ---- up-projection STATS only: BN2 applied on the fly, no h2 write ----
__global__ __launch_bounds__(256) void k_apply2up(
    const ushort_t* __restrict__ out2, const float* __restrict__ prm2,
    const ushort_t* __restrict__ wupt,
    float* __restrict__ partialT, int npts) {
    __shared__ ushort_t A[64 * 72];
    int t = threadIdx.x, bid = blockIdx.x;
    int lane = t & 63, w = t >> 6, q = lane >> 4, ln = lane & 15;
    int nbase = bid * 64;
    for (int i2 = 0; i2 < 2; i2++) {
        int slot = i2 * 256 + t;
        int row = slot >> 3, seg = slot & 7;
        int n = nbase + row;
        short8 val = (short8)0;
        if (n < npts) {
            short8 x = *(const short8*)&out2[(size_t)n * 64 + seg * 8];
            ushort_t o[8];
#pragma unroll
            for (int j = 0; j < 8; j++) {
                int c = seg * 8 + j;
                float v = prm2[c] * bf2f((ushort_t)x[j]) + prm2[64 + c];
                o[j] = f2bf(fmaxf(v, 0.f));
            }
            val = *(short8*)o;
        }
        *(short8*)&A[row * 72 + seg * 8] = val;
    }
    __syncthreads();
    int col = w * 16 + ln;
    short8 afr[4][2];
    for (int i = 0; i < 4; i++)
        for (int s = 0; s < 2; s++)
            afr[i][s] = *(const short8*)&A[(i * 16 + ln) * 72 + s * 32 + q * 8];
    float ps = 0.f, pq = 0.f;
    for (int uk = 0; uk < 8; uk++) {
        f32x4 acc[4];
        for (int i = 0; i < 4; i++) acc[i] = (f32x4)0.f;
        for (int s = 0; s < 2; s++) {
            short8 bfr = *(const short8*)&wupt[(size_t)uk * 4096 + col * 64 + s * 32 + q * 8];
            for (int i = 0; i < 4; i++)
                acc[i] = __builtin_amdgcn_mfma_f32_16x16x32_bf16(afr[i][s], bfr, acc[i], 0, 0, 0);
        }
        for (int i = 0; i < 4; i++)
            for (int r = 0; r < 4; r++) { float v = acc[i][r]; ps += v; pq += v * v; }
    }
    ps += __shfl_xor(ps, 16); ps += __shfl_xor(ps, 32);
    pq += __shfl_xor(pq, 16); pq += __shfl_xor(pq, 32);
    if (lane < 16) {
        partialT[(size_t)col * 2048 + bid] = ps;
        partialT[(size_t)(64 + col) * 2048 + bid] = pq;
    }
}

// ---- final up-projection: BN2 on the fly, BN3 + ReLU + nontemporal f32x4 stores ----
__global__ __launch_bounds__(512) void k_up(
    const ushort_t* __restrict__ out2, const ushort_t* __restrict__ wupt2,
    const float* __restrict__ prm2, const float* __restrict__ prm3,
    float* __restrict__ outp, int npts) {
    int t = threadIdx.x, bid = blockIdx.x;
    int lane = t & 63, w = t >> 6, q = lane >> 4, ln = lane & 15;
    int rbase = bid * 256 + w * 32;
    short8 afr[2][2];
#pragma unroll
    for (int g = 0; g < 2; g++) {
        int row = rbase + g * 16 + ln;
#pragma unroll
        for (int s = 0; s < 2; s++) {
            short8 v = (short8)0;
            if (row < npts) {
                short8 x = *(const short8*)&out2[(size_t)row * 64 + s * 32 + q * 8];
                ushort_t o[8];
#pragma unroll
                for (int j = 0; j < 8; j++) {
                    int c = s * 32 + q * 8 + j;
                    float vv = prm2[c] * bf2f((ushort_t)x[j]) + prm2[64 + c];
                    o[j] = f2bf(fmaxf(vv, 0.f));
                }
                v = *(short8*)o;
            }
            afr[g][s] = v;
        }
    }
    float4 sc = *(const float4*)&prm3[4 * ln];
    float4 sh = *(const float4*)&prm3[64 + 4 * ln];
    for (int uk = 0; uk < 8; uk++) {
        short8 bfr[2][4];
#pragma unroll
        for (int s = 0; s < 2; s++)
#pragma unroll
            for (int j = 0; j < 4; j++)
                bfr[s][j] = *(const short8*)&wupt2[(size_t)uk * 4096 + j * 1024 + ln * 64 + s * 32 + q * 8];
#pragma unroll
        for (int g = 0; g < 2; g++) {
            f32x4 acc[4];
#pragma unroll
            for (int j = 0; j < 4; j++) acc[j] = (f32x4)0.f;
#pragma unroll
            for (int s = 0; s < 2; s++)
#pragma unroll
                for (int j = 0; j < 4; j++)
                    acc[j] = __builtin_amdgcn_mfma_f32_16x16x32_bf16(afr[g][s], bfr[s][j], acc[j], 0, 0, 0);
#pragma unroll
            for (int r = 0; r < 4; r++) {
                int rr = rbase + g * 16 + q * 4 + r;
                if (rr < npts) {
                    f32x4 y;
                    y[0] = fmaxf(sc.x * acc[0][r] + sh.x, 0.f);
                    y[1] = fmaxf(sc.y * acc[1][r] + sh.y, 0.f);
                    y[2] = fmaxf(sc.z * acc[2][r] + sh.z, 0.f);
                    y[3] = fmaxf(sc.w * acc[3][r] + sh.w, 0.f);
                    __builtin_nontemporal_store(y, (f32x4*)&outp[((size_t)rr * 8 + uk) * 64 + 4 * ln]);
                }
            }
        }
    }
}

extern "C" void kernel_launch(void* const* d_in, const int* in_sizes, int n_in,
                              void* d_out, int out_size, void* d_ws, size_t ws_size,
                              hipStream_t stream) {
    const float* feats  = (const float*)d_in[0];
    const float* tin    = (const float*)d_in[1];
    const float* w_fuse = (const float*)d_in[2];
    const float* g1     = (const float*)d_in[3];
    const float* b1     = (const float*)d_in[4];
    const float* w_temb = (const float*)d_in[5];
    const float* b_temb = (const float*)d_in[6];
    const float* w3     = (const float*)d_in[7];
    const float* g2     = (const float*)d_in[8];
    const float* b2     = (const float*)d_in[9];
    const float* wup    = (const float*)d_in[10];
    const float* g3     = (const float*)d_in[11];
    const float* b3     = (const float*)d_in[12];
    const int* bidx     = (const int*)d_in[13];
    const int* nbr      = (const int*)d_in[14];

    int npts = in_sizes[13];  // N = 100000
    float* dout = (float*)d_out;

    // T and h live in d_out (both dead before k_up's output stream).
    // out2 lives in d_ws: k_up reads it WHILE writing the full d_out range.
    char* ob = (char*)d_out;
    ushort_t* T = (ushort_t*)ob;                              // 12.8 MB
    ushort_t* h = (ushort_t*)(ob + (size_t)npts * 128);       // 12.8 MB

    char* ws = (char*)d_ws;
    float* partialT   = (float*)ws;                                  // [128][2048] f32 = 1 MB
    float* prm        = (float*)(ws + 1048576);                      // 3 x [scale|shift]
    float* emb        = (float*)(ws + 1048576 + 4096);               // 8 x 64
    ushort_t* wfuset2 = (ushort_t*)(ws + 1048576 + 8192);            // 16 KB
    ushort_t* w3t2    = (ushort_t*)(ws + 1048576 + 8192 + 16384);    // 216 KB
    ushort_t* wupt    = (ushort_t*)(ws + 1048576 + 8192 + 16384 + 221184);          // 64 KB
    ushort_t* wupt2   = (ushort_t*)(ws + 1048576 + 8192 + 16384 + 221184 + 65536);  // 64 KB
    ushort_t* out2    = (ushort_t*)(ws + 1048576 + 8192 + 16384 + 221184 + 131072); // 12.8 MB

    int nblk  = (npts + 63) / 64;    // 1563
    int nblk2 = (npts + 127) / 128;  // 782  (conv27)
    int nblk3 = (npts + 255) / 256;  // 391  (k_up)
    int napp  = (npts * 8 + 255) / 256;

    k_prep<<<721, 256, 0, stream>>>(w_fuse, w3, wup, tin, w_temb, b_temb, emb,
                                    wfuset2, w3t2, wupt, wupt2);
    k_gemm_fuse<<<nblk, 256, 0, stream>>>(feats, wfuset2, T, partialT, npts);
    k_finalize<<<64, 256, 0, stream>>>(partialT, nblk, 1.f / npts, g1, b1, prm);
    k_apply1<<<napp, 256, 0, stream>>>(T, prm, emb, bidx, h, npts);
    k_conv27<<<nblk2, 512, 0, stream>>>(h, w3t2, nbr, out2, partialT, npts);
    k_finalize<<<64, 256, 0, stream>>>(partialT, nblk2, 1.f / npts, g2, b2, prm + 128);
    k_apply2up<<<nblk, 256, 0, stream>>>(out2, prm + 128, wupt, partialT, npts);
    k_finalize<<<64, 256, 0, stream>>>(partialT, nblk, 1.f / (8.f * npts), g3, b3, prm + 256);
    k_up<<<nblk3, 512, 0, stream>>>(out2, wupt2, prm + 128, prm + 256, dout, npts);
}

// Round 17
// 158.927 us; speedup vs baseline: 1.0999x; 1.0999x over previous
//
#include <hip/hip_runtime.h>

#define EPSV 1e-5f

typedef __attribute__((ext_vector_type(8))) short short8;
typedef __attribute__((ext_vector_type(4))) short s16x4;
typedef __attribute__((ext_vector_type(4))) float f32x4;
typedef unsigned short ushort_t;

__device__ inline ushort_t f2bf(float f) {
    unsigned int x = __builtin_bit_cast(unsigned int, f);
    unsigned int r = (x + 0x7fffu + ((x >> 16) & 1u)) >> 16;
    return (ushort_t)r;
}
__device__ inline float bf2f(ushort_t u) {
    return __builtin_bit_cast(float, (unsigned int)u << 16);
}

// ---- weight prep (col-interleaved layouts) + time embedding (block 720) ----
__global__ __launch_bounds__(256) void k_prep(
    const float* __restrict__ w_fuse, const float* __restrict__ w3,
    const float* __restrict__ wup,
    const float* __restrict__ tin, const float* __restrict__ w_temb,
    const float* __restrict__ b_temb, float* __restrict__ emb,
    ushort_t* __restrict__ wfuset2, ushort_t* __restrict__ w3t2,
    ushort_t* __restrict__ wupt, ushort_t* __restrict__ wupt2) {
    if (blockIdx.x == 720) {
        __shared__ float st[8 * 256];
        int t = threadIdx.x;
        for (int i = t; i < 2048; i += 256) { float v = tin[i]; st[i] = v / (1.f + __expf(-v)); }
        __syncthreads();
        for (int p = t; p < 512; p += 256) {
            int bb = p >> 6, c = p & 63;
            float acc = b_temb[c];
            for (int e = 0; e < 256; e++) acc += st[bb * 256 + e] * w_temb[e * 64 + c];
            emb[bb * 64 + c] = acc;
        }
        return;
    }
    int i = blockIdx.x * 256 + threadIdx.x;
    if (i < 8192) {
        int kk = i & 127, ln = (i >> 7) & 15, j = i >> 11;
        wfuset2[i] = f2bf(w_fuse[kk * 64 + 4 * ln + j]);
    } else if (i < 118784) {
        int p = i - 8192;
        int kk = p & 63, ln = (p >> 6) & 15, j = (p >> 10) & 3, k = p >> 12;
        w3t2[p] = f2bf(w3[k * 4096 + kk * 64 + 4 * ln + j]);
    } else if (i < 151552) {
        int p = i - 118784;
        int uk = p >> 12, r = p & 4095, f = r >> 6, c = r & 63;
        wupt[p] = f2bf(wup[uk * 4096 + c * 64 + f]);
    } else if (i < 184320) {
        int p = i - 151552;
        int kk = p & 63, ln = (p >> 6) & 15, j = (p >> 10) & 3, uk = p >> 12;
        wupt2[p] = f2bf(wup[uk * 4096 + kk * 64 + 4 * ln + j]);
    }
}

// ---- K1: T(bf16) = feats @ w_fuse. Row-owning waves, direct loads. ----
__global__ __launch_bounds__(256) void k_gemm_fuse(
    const float* __restrict__ feats, const ushort_t* __restrict__ wfuset2,
    ushort_t* __restrict__ T, float* __restrict__ partialT, int npts) {
    __shared__ float sm[4][128];
    int t = threadIdx.x, bid = blockIdx.x;
    int lane = t & 63, w = t >> 6, q = lane >> 4, ln = lane & 15;
    int rbase = bid * 64 + w * 16;
    int row = rbase + ln;
    bool rv = row < npts;
    short8 afr[4];
#pragma unroll
    for (int s = 0; s < 4; s++) {
        short8 v = (short8)0;
        if (rv) {
            const float* src = feats + (size_t)row * 128 + s * 32 + q * 8;
            float4 a = *(const float4*)src;
            float4 b = *(const float4*)(src + 4);
            ushort_t u[8] = {f2bf(a.x), f2bf(a.y), f2bf(a.z), f2bf(a.w),
                             f2bf(b.x), f2bf(b.y), f2bf(b.z), f2bf(b.w)};
            v = *(short8*)u;
        }
        afr[s] = v;
    }
    f32x4 acc[4];
#pragma unroll
    for (int j = 0; j < 4; j++) acc[j] = (f32x4)0.f;
#pragma unroll
    for (int s = 0; s < 4; s++)
#pragma unroll
        for (int j = 0; j < 4; j++) {
            short8 bfr = *(const short8*)&wfuset2[j * 2048 + ln * 128 + s * 32 + q * 8];
            acc[j] = __builtin_amdgcn_mfma_f32_16x16x32_bf16(afr[s], bfr, acc[j], 0, 0, 0);
        }
    float ps[4] = {0, 0, 0, 0}, pq[4] = {0, 0, 0, 0};
#pragma unroll
    for (int r = 0; r < 4; r++) {
        int rr = rbase + q * 4 + r;
        ushort_t o[4];
#pragma unroll
        for (int j = 0; j < 4; j++) {
            float v = acc[j][r];
            ps[j] += v; pq[j] += v * v;
            o[j] = f2bf(v);
        }
        if (rr < npts) *(s16x4*)&T[(size_t)rr * 64 + 4 * ln] = *(s16x4*)o;
    }
#pragma unroll
    for (int j = 0; j < 4; j++) {
        ps[j] += __shfl_xor(ps[j], 16); ps[j] += __shfl_xor(ps[j], 32);
        pq[j] += __shfl_xor(pq[j], 16); pq[j] += __shfl_xor(pq[j], 32);
    }
    if (lane < 16) {
#pragma unroll
        for (int j = 0; j < 4; j++) {
            sm[w][ln * 4 + j] = ps[j];
            sm[w][64 + ln * 4 + j] = pq[j];
        }
    }
    __syncthreads();
    if (t < 128)
        partialT[(size_t)t * 2048 + bid] = sm[0][t] + sm[1][t] + sm[2][t] + sm[3][t];
}

// ---- finalize BN: 64 blocks, one channel each; coalesced reads of partialT ----
__global__ __launch_bounds__(256) void k_finalize(
    const float* __restrict__ partialT, int nrows, float inv_count,
    const float* __restrict__ g, const float* __restrict__ b, float* __restrict__ prm) {
    int c = blockIdx.x;
    int t = threadIdx.x;
    float S = 0.f, Q = 0.f;
    for (int r = t; r < nrows; r += 256) {
        S += partialT[(size_t)c * 2048 + r];
        Q += partialT[(size_t)(64 + c) * 2048 + r];
    }
#pragma unroll
    for (int d = 1; d < 64; d <<= 1) { S += __shfl_xor(S, d); Q += __shfl_xor(Q, d); }
    __shared__ float sS[4], sQ[4];
    int w = t >> 6;
    if ((t & 63) == 0) { sS[w] = S; sQ[w] = Q; }
    __syncthreads();
    if (t == 0) {
        float s = sS[0] + sS[1] + sS[2] + sS[3];
        float qq = sQ[0] + sQ[1] + sQ[2] + sQ[3];
        float mean = s * inv_count;
        float var = qq * inv_count - mean * mean;
        float scale = g[c] * rsqrtf(var + EPSV);
        prm[c] = scale;
        prm[64 + c] = b[c] - mean * scale;
    }
}

// ---- apply BN1 + ReLU + emb -> h (bf16) ----
__global__ __launch_bounds__(256) void k_apply1(
    const ushort_t* __restrict__ T, const float* __restrict__ prm,
    const float* __restrict__ emb, const int* __restrict__ bidx,
    ushort_t* __restrict__ h, int npts) {
    int tid = blockIdx.x * 256 + threadIdx.x;
    if (tid >= npts * 8) return;
    int row = tid >> 3, c0 = (tid & 7) * 8;
    int bi = bidx[row];
    short8 x = *(const short8*)&T[(size_t)row * 64 + c0];
    ushort_t o[8];
#pragma unroll
    for (int j = 0; j < 8; j++) {
        int c = c0 + j;
        float v = prm[c] * bf2f((ushort_t)x[j]) + prm[64 + c];
        v = fmaxf(v, 0.f) + emb[bi * 64 + c];
        o[j] = f2bf(v);
    }
    *(short8*)&h[(size_t)row * 64 + c0] = *(short8*)o;
}

// ---- K4: 27-offset gather-GEMM. 8 waves x 32 rows = 256 rows/block,
//      LDS-staged B (dbuf), exec-masked reg A-gathers (only valid lanes fetch). ----
__global__ __launch_bounds__(512, 2) void k_conv27(
    const ushort_t* __restrict__ h, const ushort_t* __restrict__ w3t2,
    const int* __restrict__ nbr,
    ushort_t* __restrict__ out2, float* __restrict__ partialT, int npts) {
    __shared__ ushort_t Bl[2][4 * 4096];   // 2 x 32 KB, fragment-major per k-tile
    __shared__ float sm[8][128];
    int nwg = gridDim.x;
    int qc = nwg >> 3, rm = nwg & 7;
    int xcd = blockIdx.x & 7, pos = blockIdx.x >> 3;
    int bid = (xcd < rm ? xcd * (qc + 1) : rm * (qc + 1) + (xcd - rm) * qc) + pos;
    int t = threadIdx.x;
    int lane = t & 63, w = t >> 6, q = lane >> 4, ln = lane & 15;
    int rbase = bid * 256 + w * 32;
    int row0 = rbase + ln, row1 = rbase + 16 + ln;
    bool rv0 = row0 < npts, rv1 = row1 < npts;
    // fragment-major staging map (verified R6): dest byte D = t*16
    int D = t * 16;
    int blk = D >> 10, lane_d = (D >> 4) & 63;
    int srcByte = (blk >> 1) * 2048 + (lane_d & 15) * 128 + (blk & 1) * 64 + (lane_d >> 4) * 16;
    const char* wsrc = (const char*)w3t2 + srcByte;
    char* lbase0 = (char*)&Bl[0][0] + (size_t)w * 1024;  // wave-uniform; HW adds lane*16
    char* lbase1 = (char*)&Bl[1][0] + (size_t)w * 1024;
#define STAGE(kk, slot, bufp) \
    __builtin_amdgcn_global_load_lds((const unsigned int*)(wsrc + (size_t)(kk) * 8192), \
                                     (unsigned int*)((bufp) + (size_t)(slot) * 8192), 16, 0, 0)
    STAGE(0, 0, lbase0); STAGE(1, 1, lbase0); STAGE(2, 2, lbase0); STAGE(3, 3, lbase0);
    f32x4 acc[2][4];
#pragma unroll
    for (int g = 0; g < 2; g++)
#pragma unroll
        for (int j = 0; j < 4; j++) acc[g][j] = (f32x4)0.f;
    __syncthreads();   // staging of chunk 0 complete
#pragma unroll
    for (int c = 0; c < 7; c++) {
        const int nk = (c == 6) ? 3 : 4;
        int id0[4], id1[4];
#pragma unroll
        for (int r = 0; r < 4; r++)
            if (r < nk) {
                int kk = c * 4 + r;
                id0[r] = rv0 ? nbr[(size_t)kk * npts + row0] : -1;
                id1[r] = rv1 ? nbr[(size_t)kk * npts + row1] : -1;
            }
        if (c < 6) {
            const int nkn = (c == 5) ? 3 : 4;
            char* nb = ((c + 1) & 1) ? lbase1 : lbase0;
#pragma unroll
            for (int r = 0; r < 4; r++)
                if (r < nkn) STAGE(4 * (c + 1) + r, r, nb);
        }
        const ushort_t* bl = (c & 1) ? &Bl[1][0] : &Bl[0][0];
#pragma unroll
        for (int r = 0; r < 4; r++) {
            if (r < nk) {
                bool any0 = __any(id0[r] >= 0), any1 = __any(id1[r] >= 0);
                if (any0 || any1) {
                    // exec-masked gathers: only valid lanes fetch
                    short8 a00 = (short8)0, a01 = (short8)0;
                    short8 a10 = (short8)0, a11 = (short8)0;
                    if (id0[r] >= 0) {
                        const ushort_t* hp0 = h + (size_t)id0[r] * 64 + q * 8;
                        a00 = *(const short8*)hp0;
                        a01 = *(const short8*)(hp0 + 32);
                    }
                    if (id1[r] >= 0) {
                        const ushort_t* hp1 = h + (size_t)id1[r] * 64 + q * 8;
                        a10 = *(const short8*)hp1;
                        a11 = *(const short8*)(hp1 + 32);
                    }
                    const ushort_t* bt = bl + r * 4096;
#pragma unroll
                    for (int j = 0; j < 4; j++) {
                        short8 b0 = *(const short8*)&bt[(j * 2 + 0) * 512 + lane * 8];
                        short8 b1 = *(const short8*)&bt[(j * 2 + 1) * 512 + lane * 8];
                        if (any0) {
                            acc[0][j] = __builtin_amdgcn_mfma_f32_16x16x32_bf16(a00, b0, acc[0][j], 0, 0, 0);
                            acc[0][j] = __builtin_amdgcn_mfma_f32_16x16x32_bf16(a01, b1, acc[0][j], 0, 0, 0);
                        }
                        if (any1) {
                            acc[1][j] = __builtin_amdgcn_mfma_f32_16x16x32_bf16(a10, b0, acc[1][j], 0, 0, 0);
                            acc[1][j] = __builtin_amdgcn_mfma_f32_16x16x32_bf16(a11, b1, acc[1][j], 0, 0, 0);
                        }
                    }
                }
            }
        }
        __syncthreads();   // next buffer staged + all waves done with this one
    }
#undef STAGE
    float ps[4] = {0, 0, 0, 0}, pq[4] = {0, 0, 0, 0};
#pragma unroll
    for (int g = 0; g < 2; g++)
#pragma unroll
        for (int r = 0; r < 4; r++) {
            int rr = rbase + g * 16 + q * 4 + r;
            ushort_t o[4];
#pragma unroll
            for (int j = 0; j < 4; j++) {
                float v = acc[g][j][r];
                ps[j] += v; pq[j] += v * v;
                o[j] = f2bf(v);
            }
            if (rr < npts) *(s16x4*)&out2[(size_t)rr * 64 + 4 * ln] = *(s16x4*)o;
        }
#pragma unroll
    for (int j = 0; j < 4; j++) {
        ps[j] += __shfl_xor(ps[j], 16); ps[j] += __shfl_xor(ps[j], 32);
        pq[j] += __shfl_xor(pq[j], 16); pq[j] += __shfl_xor(pq[j], 32);
    }
    if (lane < 16) {
#pragma unroll
        for (int j = 0; j < 4; j++) {
            sm[w][ln * 4 + j] = ps[j];
            sm[w][64 + ln * 4 + j] = pq[j];
        }
    }
    __syncthreads();
    if (t < 128) {
        float s = 0.f;
#pragma unroll
        for (int i = 0; i < 8; i++) s += sm[i][t];
        partialT[(size_t)t * 2048 + bid] = s;
    }
}

// ---- up-projection STATS only: BN2 applied on the fly, no h2 write ----
__global__ __launch_bounds__(256) void k_apply2up(
    const ushort_t* __restrict__ out2, const float* __restrict__ prm2,
    const ushort_t* __restrict__ wupt,
    float* __restrict__ partialT, int npts) {
    __shared__ ushort_t A[64 * 72];
    int t = threadIdx.x, bid = blockIdx.x;
    int lane = t & 63, w = t >> 6, q = lane >> 4, ln = lane & 15;
    int nbase = bid * 64;
    for (int i2 = 0; i2 < 2; i2++) {
        int slot = i2 * 256 + t;
        int row = slot >> 3, seg = slot & 7;
        int n = nbase + row;
        short8 val = (short8)0;
        if (n < npts) {
            short8 x = *(const short8*)&out2[(size_t)n * 64 + seg * 8];
            ushort_t o[8];
#pragma unroll
            for (int j = 0; j < 8; j++) {
                int c = seg * 8 + j;
                float v = prm2[c] * bf2f((ushort_t)x[j]) + prm2[64 + c];
                o[j] = f2bf(fmaxf(v, 0.f));
            }
            val = *(short8*)o;
        }
        *(short8*)&A[row * 72 + seg * 8] = val;
    }
    __syncthreads();
    int col = w * 16 + ln;
    short8 afr[4][2];
    for (int i = 0; i < 4; i++)
        for (int s = 0; s < 2; s++)
            afr[i][s] = *(const short8*)&A[(i * 16 + ln) * 72 + s * 32 + q * 8];
    float ps = 0.f, pq = 0.f;
    for (int uk = 0; uk < 8; uk++) {
        f32x4 acc[4];
        for (int i = 0; i < 4; i++) acc[i] = (f32x4)0.f;
        for (int s = 0; s < 2; s++) {
            short8 bfr = *(const short8*)&wupt[(size_t)uk * 4096 + col * 64 + s * 32 + q * 8];
            for (int i = 0; i < 4; i++)
                acc[i] = __builtin_amdgcn_mfma_f32_16x16x32_bf16(afr[i][s], bfr, acc[i], 0, 0, 0);
        }
        for (int i = 0; i < 4; i++)
            for (int r = 0; r < 4; r++) { float v = acc[i][r]; ps += v; pq += v * v; }
    }
    ps += __shfl_xor(ps, 16); ps += __shfl_xor(ps, 32);
    pq += __shfl_xor(pq, 16); pq += __shfl_xor(pq, 32);
    if (lane < 16) {
        partialT[(size_t)col * 2048 + bid] = ps;
        partialT[(size_t)(64 + col) * 2048 + bid] = pq;
    }
}

// ---- final up-projection: BN2 on the fly, BN3 + ReLU + nontemporal f32x4 stores ----
__global__ __launch_bounds__(512) void k_up(
    const ushort_t* __restrict__ out2, const ushort_t* __restrict__ wupt2,
    const float* __restrict__ prm2, const float* __restrict__ prm3,
    float* __restrict__ outp, int npts) {
    int t = threadIdx.x, bid = blockIdx.x;
    int lane = t & 63, w = t >> 6, q = lane >> 4, ln = lane & 15;
    int rbase = bid * 256 + w * 32;
    short8 afr[2][2];
#pragma unroll
    for (int g = 0; g < 2; g++) {
        int row = rbase + g * 16 + ln;
#pragma unroll
        for (int s = 0; s < 2; s++) {
            short8 v = (short8)0;
            if (row < npts) {
                short8 x = *(const short8*)&out2[(size_t)row * 64 + s * 32 + q * 8];
                ushort_t o[8];
#pragma unroll
                for (int j = 0; j < 8; j++) {
                    int c = s * 32 + q * 8 + j;
                    float vv = prm2[c] * bf2f((ushort_t)x[j]) + prm2[64 + c];
                    o[j] = f2bf(fmaxf(vv, 0.f));
                }
                v = *(short8*)o;
            }
            afr[g][s] = v;
        }
    }
    float4 sc = *(const float4*)&prm3[4 * ln];
    float4 sh = *(const float4*)&prm3[64 + 4 * ln];
    for (int uk = 0; uk < 8; uk++) {
        short8 bfr[2][4];
#pragma unroll
        for (int s = 0; s < 2; s++)
#pragma unroll
            for (int j = 0; j < 4; j++)
                bfr[s][j] = *(const short8*)&wupt2[(size_t)uk * 4096 + j * 1024 + ln * 64 + s * 32 + q * 8];
#pragma unroll
        for (int g = 0; g < 2; g++) {
            f32x4 acc[4];
#pragma unroll
            for (int j = 0; j < 4; j++) acc[j] = (f32x4)0.f;
#pragma unroll
            for (int s = 0; s < 2; s++)
#pragma unroll
                for (int j = 0; j < 4; j++)
                    acc[j] = __builtin_amdgcn_mfma_f32_16x16x32_bf16(afr[g][s], bfr[s][j], acc[j], 0, 0, 0);
#pragma unroll
            for (int r = 0; r < 4; r++) {
                int rr = rbase + g * 16 + q * 4 + r;
                if (rr < npts) {
                    f32x4 y;
                    y[0] = fmaxf(sc.x * acc[0][r] + sh.x, 0.f);
                    y[1] = fmaxf(sc.y * acc[1][r] + sh.y, 0.f);
                    y[2] = fmaxf(sc.z * acc[2][r] + sh.z, 0.f);
                    y[3] = fmaxf(sc.w * acc[3][r] + sh.w, 0.f);
                    __builtin_nontemporal_store(y, (f32x4*)&outp[((size_t)rr * 8 + uk) * 64 + 4 * ln]);
                }
            }
        }
    }
}

extern "C" void kernel_launch(void* const* d_in, const int* in_sizes, int n_in,
                              void* d_out, int out_size, void* d_ws, size_t ws_size,
                              hipStream_t stream) {
    const float* feats  = (const float*)d_in[0];
    const float* tin    = (const float*)d_in[1];
    const float* w_fuse = (const float*)d_in[2];
    const float* g1     = (const float*)d_in[3];
    const float* b1     = (const float*)d_in[4];
    const float* w_temb = (const float*)d_in[5];
    const float* b_temb = (const float*)d_in[6];
    const float* w3     = (const float*)d_in[7];
    const float* g2     = (const float*)d_in[8];
    const float* b2     = (const float*)d_in[9];
    const float* wup    = (const float*)d_in[10];
    const float* g3     = (const float*)d_in[11];
    const float* b3     = (const float*)d_in[12];
    const int* bidx     = (const int*)d_in[13];
    const int* nbr      = (const int*)d_in[14];

    int npts = in_sizes[13];  // N = 100000
    float* dout = (float*)d_out;

    // T and h live in d_out (both dead before k_up's output stream).
    // out2 lives in d_ws: k_up reads it WHILE writing the full d_out range.
    char* ob = (char*)d_out;
    ushort_t* T = (ushort_t*)ob;                              // 12.8 MB
    ushort_t* h = (ushort_t*)(ob + (size_t)npts * 128);       // 12.8 MB

    char* ws = (char*)d_ws;
    float* partialT   = (float*)ws;                                  // [128][2048] f32 = 1 MB
    float* prm        = (float*)(ws + 1048576);                      // 3 x [scale|shift]
    float* emb        = (float*)(ws + 1048576 + 4096);               // 8 x 64
    ushort_t* wfuset2 = (ushort_t*)(ws + 1048576 + 8192);            // 16 KB
    ushort_t* w3t2    = (ushort_t*)(ws + 1048576 + 8192 + 16384);    // 216 KB
    ushort_t* wupt    = (ushort_t*)(ws + 1048576 + 8192 + 16384 + 221184);          // 64 KB
    ushort_t* wupt2   = (ushort_t*)(ws + 1048576 + 8192 + 16384 + 221184 + 65536);  // 64 KB
    ushort_t* out2    = (ushort_t*)(ws + 1048576 + 8192 + 16384 + 221184 + 131072); // 12.8 MB

    int nblk  = (npts + 63) / 64;    // 1563
    int nblk3 = (npts + 255) / 256;  // 391
    int napp  = (npts * 8 + 255) / 256;

    k_prep<<<721, 256, 0, stream>>>(w_fuse, w3, wup, tin, w_temb, b_temb, emb,
                                    wfuset2, w3t2, wupt, wupt2);
    k_gemm_fuse<<<nblk, 256, 0, stream>>>(feats, wfuset2, T, partialT, npts);
    k_finalize<<<64, 256, 0, stream>>>(partialT, nblk, 1.f / npts, g1, b1, prm);
    k_apply1<<<napp, 256, 0, stream>>>(T, prm, emb, bidx, h, npts);
    k_conv27<<<nblk3, 512, 0, stream>>>(h, w3t2, nbr, out2, partialT, npts);
    k_finalize<<<64, 256, 0, stream>>>(partialT, nblk3, 1.f / npts, g2, b2, prm + 128);
    k_apply2up<<<nblk, 256, 0, stream>>>(out2, prm + 128, wupt, partialT, npts);
    k_finalize<<<64, 256, 0, stream>>>(partialT, nblk, 1.f / (8.f * npts), g3, b3, prm + 256);
    k_up<<<nblk3, 512, 0, stream>>>(out2, wupt2, prm + 128, prm + 256, dout, npts);
}